// Round 6
// baseline (155.298 us; speedup 1.0000x reference)
//
#include <hip/hip_runtime.h>
#include <hip/hip_bf16.h>
#include <math.h>

// Problem shape (fixed by setup_inputs):
//   x: [2, 64, 192, 192] fp32, scale=scale2=2 -> sh=sw=384, out: [2,64,384,384] fp32
#define BN  2
#define CN  64
#define HN  192
#define WN  192
#define SH  384
#define SW  384
#define HW  (HN * WN)
#define NPIX (BN * HN * WN)   // 73728

typedef __attribute__((ext_vector_type(8))) short bf16x8;
typedef __attribute__((ext_vector_type(4))) float f32x4;

#define CPAD  72                      // ushort stride per position ch-vector: 144B, 16B-aligned
#define TRB   (BN * HN * 3)           // 1152 transpose blocks / feat blocks
#define TBLB  64                      // table blocks in prepass

// exact round-to-nearest-even fp32 -> bf16 bits
__device__ inline unsigned short f2bf(float f) {
    unsigned int u = __float_as_uint(f);
    u += 0x7fffu + ((u >> 16) & 1u);
    return (unsigned short)(u >> 16);
}
__device__ inline unsigned int pkbf(float a, float b) {
    return (unsigned int)f2bf(a) | ((unsigned int)f2bf(b) << 16);
}

// ---------------------------------------------------------------------------
// MLP helper: one wave, lane = hidden unit. Returns head partial sums p[6].
// ---------------------------------------------------------------------------
__device__ inline void run_mlp(int lane, float in0, float in1, float chv, float cwv,
    const float* __restrict__ wb1, const float* __restrict__ bb1,
    const float* __restrict__ wb2, const float* __restrict__ bb2,
    const float* __restrict__ wr,  const float* __restrict__ wo, float p[6])
{
    float4 w1 = ((const float4*)wb1)[lane];
    float h1 = fmaxf(bb1[lane] + w1.x * in0 + w1.y * in1 + w1.z * chv + w1.w * cwv, 0.f);
    const float4* w2row = (const float4*)(wb2 + lane * 64);
    float acc = bb2[lane];
#pragma unroll
    for (int q = 0; q < 16; ++q) {
        float4 wv = w2row[q];
        acc += wv.x * __shfl(h1, q * 4 + 0)
             + wv.y * __shfl(h1, q * 4 + 1)
             + wv.z * __shfl(h1, q * 4 + 2)
             + wv.w * __shfl(h1, q * 4 + 3);
    }
    float h2 = fmaxf(acc, 0.f);
#pragma unroll
    for (int e = 0; e < 4; ++e) p[e] = wr[e * 64 + lane] * h2;
#pragma unroll
    for (int e = 0; e < 2; ++e) p[4 + e] = wo[e * 64 + lane] * h2;
#pragma unroll
    for (int m = 1; m < 64; m <<= 1) {
#pragma unroll
        for (int e = 0; e < 6; ++e) p[e] += __shfl_xor(p[e], m);
    }
}

// ---------------------------------------------------------------------------
// Kernel 0 (v9 NEW): prepass.
//   blocks [0, TRB):   transpose+convert x [B,C,H,W] fp32 -> xt [B,H,W,C] bf16
//                      (same f2bf rounding -> feat GEMM inputs bit-identical).
//   block  TRB:        precompute 9-tap A-fragments (sobel folded into taps)
//                      into tblW[w][t][kc][lane] bf16x8, fragment-ordered.
//                      Removes ~600 redundant VALU per wave from feat.
//   blocks > TRB:      routing/offset table + fused expert matrices (v5 logic).
// ---------------------------------------------------------------------------
__global__ __launch_bounds__(256) void prepass_kernel(
    const float* __restrict__ x,     // [B,64,H,W]
    const float* __restrict__ wcv,   // [64,192]
    const float* __restrict__ wb1, const float* __restrict__ bb1,
    const float* __restrict__ wb2, const float* __restrict__ bb2,
    const float* __restrict__ wr,  const float* __restrict__ br,
    const float* __restrict__ wo,  const float* __restrict__ bo,
    const float* __restrict__ wce, const float* __restrict__ wee,
    const int* __restrict__ scale_p, const int* __restrict__ scale2_p,
    unsigned short* __restrict__ xt,    // [B,H,W,64] bf16
    unsigned short* __restrict__ tblW,  // [4][9][2][64] bf16x8
    float* __restrict__ tblEntry, unsigned short* __restrict__ tblM)
{
    __shared__ __attribute__((aligned(16))) unsigned short sm[64 * CPAD]; // 9216 B

    int tid  = threadIdx.x;
    int lane = tid & 63;
    int bi = blockIdx.x;

    if (bi < TRB) {
        // ---------------- transpose+convert 64 cols x 64 ch ---------------
        int jt = bi % 3;
        int t2 = bi / 3;
        int i  = t2 % HN;
        int b  = t2 / HN;
        int j0 = jt * 64;
        int w  = tid >> 6;
        int c0 = w * 16;

        const float* xp = x + (size_t)b * CN * HW + (size_t)i * WN + j0 + lane;
#pragma unroll
        for (int k = 0; k < 16; k += 2) {
            float f0 = xp[(size_t)(c0 + k) * HW];
            float f1 = xp[(size_t)(c0 + k + 1) * HW];
            *(unsigned int*)(sm + lane * CPAD + c0 + k) = pkbf(f0, f1);
        }
        __syncthreads();
        size_t obase = (((size_t)b * HN + i) * WN + j0) * 64;
#pragma unroll
        for (int it = 0; it < 2; ++it) {
            int task = tid + it * 256;       // 0..511
            int jj = task >> 3, oc = task & 7;
            uint4 v = *(const uint4*)(sm + jj * CPAD + oc * 8);
            *(uint4*)(xt + obase + (size_t)jj * 64 + oc * 8) = v;
        }
        return;
    }

    if (bi == TRB) {
        // ---------------- A-fragment precompute (one block) ----------------
        const float KXc[9] = {-1.f, 0.f, 1.f, -2.f, 0.f, 2.f, -1.f, 0.f, 1.f};
        const float KYc[9] = {-1.f, -2.f, -1.f, 0.f, 0.f, 0.f, 1.f, 2.f, 1.f};
        int wv = tid >> 6;
        int o  = (wv << 4) + (lane & 15);
        const float* wp = wcv + o * 192;
        float v0[2][8], v1[2][8], v2[2][8];
#pragma unroll
        for (int kc = 0; kc < 2; ++kc) {
            int kb = kc * 32 + (lane >> 4) * 8;
            float4 a0 = *(const float4*)(wp + kb);
            float4 a1 = *(const float4*)(wp + kb + 4);
            float4 b0 = *(const float4*)(wp + 64 + kb);
            float4 b1 = *(const float4*)(wp + 64 + kb + 4);
            float4 c0 = *(const float4*)(wp + 128 + kb);
            float4 c1 = *(const float4*)(wp + 128 + kb + 4);
            v0[kc][0]=a0.x; v0[kc][1]=a0.y; v0[kc][2]=a0.z; v0[kc][3]=a0.w;
            v0[kc][4]=a1.x; v0[kc][5]=a1.y; v0[kc][6]=a1.z; v0[kc][7]=a1.w;
            v1[kc][0]=b0.x; v1[kc][1]=b0.y; v1[kc][2]=b0.z; v1[kc][3]=b0.w;
            v1[kc][4]=b1.x; v1[kc][5]=b1.y; v1[kc][6]=b1.z; v1[kc][7]=b1.w;
            v2[kc][0]=c0.x; v2[kc][1]=c0.y; v2[kc][2]=c0.z; v2[kc][3]=c0.w;
            v2[kc][4]=c1.x; v2[kc][5]=c1.y; v2[kc][6]=c1.z; v2[kc][7]=c1.w;
        }
#pragma unroll
        for (int t = 0; t < 9; ++t) {
#pragma unroll
            for (int kc = 0; kc < 2; ++kc) {
                bf16x8 a;
#pragma unroll
                for (int e = 0; e < 8; ++e) {
                    float f = v1[kc][e] * KXc[t] + v2[kc][e] * KYc[t];
                    if (t == 4) f += v0[kc][e];
                    a[e] = (short)f2bf(f);
                }
                *(bf16x8*)(void*)(tblW + (size_t)(((wv * 9 + t) * 2 + kc) * 64 + lane) * 8) = a;
            }
        }
        return;
    }

    // ---------------- table path (LDS aliased onto sm) ---------------------
    {
        float* wcmL = (float*)sm;              // [2][512]
        float* wemL = wcmL + 1024;             // [2][512]
        float* reL  = wemL + 1024;             // [8]   (8224 B <= 9216)

        int sc = scale_p[0], sc2 = scale2_p[0];
        float scale = (float)sc, scale2 = (float)sc2;
        float in0 = 1.f / scale2, in1 = 1.f / scale;
        bool fast = (sc2 == 2 && sc <= 16);
        int tb = bi - (TRB + 1);

        if (fast) {
            int pi = tb;
            if (pi >= sc) return;
            if (tid < 64) {
                float ih = (pi + 0.5f) / scale;
                float chv = ih - floorf(ih + 0.001f) - 0.5f;
                float p0[6], p1[6];
                {
                    float iw = 0.5f / scale2;
                    float cwv = iw - floorf(iw + 0.001f) - 0.5f;
                    run_mlp(lane, in0, in1, chv, cwv, wb1, bb1, wb2, bb2, wr, wo, p0);
                }
                {
                    float iw = 1.5f / scale2;
                    float cwv = iw - floorf(iw + 0.001f) - 0.5f;
                    run_mlp(lane, in0, in1, chv, cwv, wb1, bb1, wb2, bb2, wr, wo, p1);
                }
                if (lane == 0) {
                    float* t0 = tblEntry + (pi * 2 + 0) * 8;
                    float* t1 = tblEntry + (pi * 2 + 1) * 8;
#pragma unroll
                    for (int e = 0; e < 4; ++e) {
                        float rE = 1.f / (1.f + expf(-(p0[e] + br[e])));
                        float rO = 1.f / (1.f + expf(-(p1[e] + br[e])));
                        t0[e] = rE; t1[e] = rO;
                        reL[e] = rE; reL[4 + e] = rO;
                    }
                    t0[4] = p0[4] + bo[0]; t0[5] = p0[5] + bo[1];
                    t1[4] = p1[4] + bo[0]; t1[5] = p1[5] + bo[1];
                }
            }
            __syncthreads();
            float reE0 = reL[0], reE1 = reL[1], reE2 = reL[2], reE3 = reL[3];
            float reO0 = reL[4], reO1 = reL[5], reO2 = reL[6], reO3 = reL[7];
            for (int idx = tid; idx < 512; idx += 256) {
                float a = wce[idx], bq = wce[512 + idx], c = wce[1024 + idx], d = wce[1536 + idx];
                wcmL[idx]       = reE0 * a + reE1 * bq + reE2 * c + reE3 * d;
                wcmL[512 + idx] = reO0 * a + reO1 * bq + reO2 * c + reO3 * d;
                float e_ = wee[idx], f = wee[512 + idx], g = wee[1024 + idx], h = wee[1536 + idx];
                wemL[idx]       = reE0 * e_ + reE1 * f + reE2 * g + reE3 * h;
                wemL[512 + idx] = reO0 * e_ + reO1 * f + reO2 * g + reO3 * h;
            }
            __syncthreads();
            // M[p][co][ci] = sum_k wem[p][co*8+k] * wcm[p][k*64+ci]
            int co  = tid >> 2;
            int ci0 = (tid & 3) << 4;
            float w0[8], w1[8];
#pragma unroll
            for (int k = 0; k < 8; ++k) {
                w0[k] = wemL[co * 8 + k];
                w1[k] = wemL[512 + co * 8 + k];
            }
            unsigned short* tbp = tblM + (size_t)pi * 2 * 4096;
#pragma unroll
            for (int cc = 0; cc < 16; ++cc) {
                int ci = ci0 + cc;
                float m0 = 0.f, m1 = 0.f;
#pragma unroll
                for (int k = 0; k < 8; ++k) {
                    m0 += w0[k] * wcmL[k * 64 + ci];
                    m1 += w1[k] * wcmL[512 + k * 64 + ci];
                }
                tbp[co * 64 + ci]        = f2bf(0.5f * (m0 + m1));   // Mavg
                tbp[4096 + co * 64 + ci] = f2bf(0.5f * (m0 - m1));   // Mdiff
            }
        } else {
            int w_ = (tb * 256 + tid) >> 6;
            if (w_ >= sc * sc2) return;
            int pi = w_ / sc2, pj = w_ - pi * sc2;
            float ih = (pi + 0.5f) / scale;
            float chv = ih - floorf(ih + 0.001f) - 0.5f;
            float iw = (pj + 0.5f) / scale2;
            float cwv = iw - floorf(iw + 0.001f) - 0.5f;
            float p[6];
            run_mlp(lane, in0, in1, chv, cwv, wb1, bb1, wb2, bb2, wr, wo, p);
            if (lane == 0) {
                float* tp = tblEntry + w_ * 8;
#pragma unroll
                for (int e = 0; e < 4; ++e) tp[e] = 1.f / (1.f + expf(-(p[e] + br[e])));
                tp[4] = p[4] + bo[0];
                tp[5] = p[5] + bo[1];
            }
        }
    }
}

// ---------------------------------------------------------------------------
// Kernel 1 (v9): feat 3x3-conv MFMA GEMM, NHWC-bf16 staging.
//   v8 post-mortem: gain < predicted; staging was still 64 loads + ~200 VALU
//   cvt per thread + ~600 VALU A-frag rebuild per wave, all pre-barrier.
//   v9: A-frags = 18 b128 loads from tblW; staging = 7 x {coalesced dwordx4
//   load from xt (NHWC bf16), border-select, ds_write_b128}. Zero conversion
//   VALU in the hot kernel. Same LDS layout / MFMA loop / epilogue as v8.
// ---------------------------------------------------------------------------
__global__ __launch_bounds__(256) void feat_kernel(
    const unsigned short* __restrict__ xt,    // [B,H,W,64] bf16
    const unsigned short* __restrict__ tblW,  // [4][9][2][64] bf16x8
    const float* __restrict__ bcv,            // [64]
    float* __restrict__ feat)                 // [B,64,H,W]
{
    __shared__ __attribute__((aligned(16))) unsigned short sm[198 * CPAD]; // 28512 B

    int tid  = threadIdx.x;
    int lane = tid & 63;
    int bi = blockIdx.x;
    int jt = bi % 3;
    int t2 = bi / 3;
    int i0 = t2 % HN;
    int b  = t2 / HN;
    int j0 = jt * 64;
    int w  = __builtin_amdgcn_readfirstlane(tid >> 6);

    int row = lane & 15;
    int q   = lane >> 4;

    // ---- A fragments: 18 coalesced b128 loads (precomputed taps) ----
    bf16x8 afrag[9][2];
#pragma unroll
    for (int t = 0; t < 9; ++t)
#pragma unroll
        for (int kc = 0; kc < 2; ++kc)
            afrag[t][kc] = *(const bf16x8*)(void*)(
                tblW + (size_t)(((w * 9 + t) * 2 + kc) * 64 + lane) * 8);

    // ---- stage x tile: 1584 (pos, ch-octet) tasks, 7 iters ----
#pragma unroll
    for (int it = 0; it < 7; ++it) {
        int task = tid + it * 256;
        if (task < 198 * 8) {
            int p  = task >> 3;
            int oc = task & 7;
            int rowi = p / 66;
            int col  = p - rowi * 66;
            int sr = i0 - 1 + rowi;
            int hc = j0 - 1 + col;
            bool ok = (sr >= 0) && (sr < HN) && (hc >= 0) && (hc < WN);
            int srb = ok ? sr : 0;
            int hcb = ok ? hc : 0;
            uint4 v = *(const uint4*)(xt + (((size_t)b * HN + srb) * WN + hcb) * 64 + oc * 8);
            if (!ok) v = (uint4){0u, 0u, 0u, 0u};
            *(uint4*)(sm + p * CPAD + oc * 8) = v;
        }
    }

    __syncthreads();

    // ---- MFMA: 4 n-subtiles x 9 taps x 2 k-chunks = 72 ----
    f32x4 acc[4] = {};
    const unsigned short* bb0 = sm + row * CPAD + (q << 3);
#pragma unroll
    for (int nt = 0; nt < 4; ++nt) {
#pragma unroll
        for (int t = 0; t < 9; ++t) {
            int a_ = t / 3, dxi = t - a_ * 3;
#pragma unroll
            for (int kc = 0; kc < 2; ++kc) {
                bf16x8 bv = *(const bf16x8*)(bb0 + (a_ * 66 + nt * 16 + dxi) * CPAD + kc * 32);
                acc[nt] = __builtin_amdgcn_mfma_f32_16x16x32_bf16(afrag[t][kc], bv, acc[nt], 0, 0, 0);
            }
        }
    }

    // ---- epilogue: bias + store (D: col=lane&15, och = q*4+rr) ----
    size_t rb0 = (size_t)b * CN * HW + (size_t)i0 * WN + j0 + row;
#pragma unroll
    for (int rr = 0; rr < 4; ++rr) {
        int oc = (w << 4) + q * 4 + rr;
        float bias = bcv[oc];
        size_t rowb = rb0 + (size_t)oc * HW;
#pragma unroll
        for (int nt = 0; nt < 4; ++nt)
            feat[rowb + nt * 16] = acc[nt][rr] + bias;
    }
}

// ---------------------------------------------------------------------------
// Kernel 2 (v4, unchanged): bilinear gather + fused expert GEMM + residual.
// ---------------------------------------------------------------------------
#define BKP 72   // ushort stride of Bs rows: multiple of 8 -> 16B-aligned b128
__global__ __launch_bounds__(256) void out_kernel(
    const float* __restrict__ feat,      // [B,64,H,W]
    const float* __restrict__ tblEntry,  // [256][8]
    const unsigned short* __restrict__ tblM,  // [pi][2][64][64] bf16
    const float* __restrict__ wce,       // [4,8,64]
    const float* __restrict__ wee,       // [4,64,8]
    const int* __restrict__ scale_p, const int* __restrict__ scale2_p,
    float* __restrict__ out)             // [B,64,SH,SW]
{
    __shared__ __attribute__((aligned(16))) float smem[64 * 65 + 64 * (BKP / 2)];
    float* fea32 = smem;                               // [px][65] fp32
    unsigned short* Bsv = (unsigned short*)(smem + 64 * 65);  // [px][BKP] bf16
    float* midp = smem;                                // generic-path alias

    int Bk = blockIdx.x;
    int T = gridDim.x;                           // 4608, %8==0
    int t = ((T & 7) == 0) ? ((Bk & 7) * (T >> 3) + (Bk >> 3)) : Bk;

    int tid = threadIdx.x;
    int g = __builtin_amdgcn_readfirstlane(tid >> 6);
    int lane = tid & 63;
    int pix0 = t * 64;
    int b = pix0 / (SH * SW);
    int r0 = pix0 - b * SH * SW;
    int i = r0 / SW;
    int j0 = r0 - i * SW;
    int j = j0 + lane;
    int r = r0 + lane;

    int sc = scale_p[0], sc2 = scale2_p[0];
    float scale = (float)sc, scale2 = (float)sc2;
    int pi = i - (i / sc) * sc;          // wave-uniform
    int pj = j - (j / sc2) * sc2;        // per-lane
    int entry = pi * sc2 + pj;
    float offx = tblEntry[entry * 8 + 4];
    float offy = tblEntry[entry * 8 + 5];

    const float inv_wm1 = 2.f / (float)(WN - 1);
    const float inv_hm1 = 2.f / (float)(HN - 1);
    float gx = ((j + 0.5f) / scale2 - 0.5f) * inv_wm1 - 1.f + offx * inv_wm1;
    float gy = ((i + 0.5f) / scale  - 0.5f) * inv_hm1 - 1.f + offy * inv_hm1;

    float ix = ((gx + 1.f) * WN - 1.f) * 0.5f;
    float iy = ((gy + 1.f) * HN - 1.f) * 0.5f;
    float fx0 = floorf(ix), fy0 = floorf(iy);
    int x0 = (int)fx0, y0 = (int)fy0;
    float wx1 = ix - fx0, wx0 = 1.f - wx1;
    float wy1 = iy - fy0, wy0 = 1.f - wy1;

    bool vx0 = (x0 >= 0) && (x0 <= WN - 1);
    bool vx1 = (x0 + 1 >= 0) && (x0 + 1 <= WN - 1);
    bool vy0 = (y0 >= 0) && (y0 <= HN - 1);
    bool vy1 = (y0 + 1 >= 0) && (y0 + 1 <= HN - 1);
    bool v00 = vx0 && vy0, v10 = vx1 && vy0, v01 = vx0 && vy1, v11 = vx1 && vy1;
    float w00 = wx0 * wy0, w10 = wx1 * wy0, w01 = wx0 * wy1, w11 = wx1 * wy1;

    int i00 = y0 * WN + x0;
    int i10 = i00 + 1;
    int i01 = i00 + WN;
    int i11 = i01 + 1;

    const float* fb = feat + (size_t)b * CN * HW;

    float f0[16];
#pragma unroll
    for (int cc = 0; cc < 16; ++cc) {
        const float* fc = fb + (size_t)(g * 16 + cc) * HW;
        float a  = v00 ? fc[i00] : 0.f;
        float bq = v10 ? fc[i10] : 0.f;
        float cq = v01 ? fc[i01] : 0.f;
        float dq = v11 ? fc[i11] : 0.f;
        f0[cc] = a * w00 + bq * w10 + cq * w01 + dq * w11;
    }

    bool fast = (sc2 == 2 && sc <= 16);
    if (fast) {
        // ---- stage fea0: fp32 [px][65] + bf16 [px][BKP] ----
        int px = lane;
#pragma unroll
        for (int cc = 0; cc < 16; ++cc)
            fea32[px * 65 + g * 16 + cc] = f0[cc];
#pragma unroll
        for (int cc = 0; cc < 16; cc += 2) {
            unsigned int pk = (unsigned int)f2bf(f0[cc]) | ((unsigned int)f2bf(f0[cc + 1]) << 16);
            *(unsigned int*)(Bsv + px * BKP + g * 16 + cc) = pk;
        }

        // ---- A fragments (global, issue before barrier): Mavg/Mdiff rows ----
        int row = lane & 15;
        int kb  = (lane >> 4) << 3;
        const unsigned short* Mb = tblM + (size_t)pi * 2 * 4096 + (g * 16 + row) * 64 + kb;
        bf16x8 a1[2], a2[2];
        a1[0] = *(const bf16x8*)(Mb);
        a1[1] = *(const bf16x8*)(Mb + 32);
        a2[0] = *(const bf16x8*)(Mb + 4096);
        a2[1] = *(const bf16x8*)(Mb + 4096 + 32);

        __syncthreads();

        // ---- MFMA: D1 = Mavg@fea0, D2 = Mdiff@fea0 (M=16/wave, N=64, K=64) ----
        f32x4 acc1[4] = {}, acc2[4] = {};
        const unsigned short* bp = Bsv + (lane & 15) * BKP + kb;
#pragma unroll
        for (int nt = 0; nt < 4; ++nt) {
            const unsigned short* bnt = bp + nt * 16 * BKP;
#pragma unroll
            for (int ks = 0; ks < 2; ++ks) {
                bf16x8 bf = *(const bf16x8*)(bnt + ks * 32);
                acc1[nt] = __builtin_amdgcn_mfma_f32_16x16x32_bf16(a1[ks], bf, acc1[nt], 0, 0, 0);
                acc2[nt] = __builtin_amdgcn_mfma_f32_16x16x32_bf16(a2[ks], bf, acc2[nt], 0, 0, 0);
            }
        }

        // ---- epilogue: residual (fp32 LDS) + parity sign, store ----
        int q = lane >> 4;
#pragma unroll
        for (int rr = 0; rr < 4; ++rr) {
            int c = g * 16 + q * 4 + rr;
            size_t rowb = (size_t)(b * CN + c) * SH * SW + r0;
#pragma unroll
            for (int nt = 0; nt < 4; ++nt) {
                int n = (lane & 15) + nt * 16;
                float sgn = (n & 1) ? -1.f : 1.f;
                float v = fea32[n * 65 + c] + acc1[nt][rr] + sgn * acc2[nt][rr];
                out[rowb + n] = v;
            }
        }
    } else {
        float4 rw = *(const float4*)(tblEntry + entry * 8);
        float re[4] = {rw.x, rw.y, rw.z, rw.w};
        float part[4][8];
#pragma unroll
        for (int e = 0; e < 4; ++e) {
#pragma unroll
            for (int k = 0; k < 8; ++k) {
                const float* wrow = wce + (e * 8 + k) * 64 + g * 16;
                float d = 0.f;
#pragma unroll
                for (int cc = 0; cc < 16; ++cc) d += wrow[cc] * f0[cc];
                part[e][k] = d;
            }
        }
#pragma unroll
        for (int k = 0; k < 8; ++k) {
            float m = re[0] * part[0][k] + re[1] * part[1][k]
                    + re[2] * part[2][k] + re[3] * part[3][k];
            midp[(g * 64 + lane) * 9 + k] = m;
        }
        __syncthreads();
        float mid[8];
#pragma unroll
        for (int k = 0; k < 8; ++k)
            mid[k] = midp[(0 * 64 + lane) * 9 + k] + midp[(1 * 64 + lane) * 9 + k]
                   + midp[(2 * 64 + lane) * 9 + k] + midp[(3 * 64 + lane) * 9 + k];
#pragma unroll
        for (int cc = 0; cc < 16; ++cc) {
            int c = g * 16 + cc;
            float v = f0[cc];
#pragma unroll
            for (int e = 0; e < 4; ++e) {
                const float* wrow = wee + (e * 64 + c) * 8;
                float d = 0.f;
#pragma unroll
                for (int k = 0; k < 8; ++k) d += wrow[k] * mid[k];
                v += re[e] * d;
            }
            out[(size_t)(b * CN + c) * SH * SW + r] = v;
        }
    }
}

extern "C" void kernel_launch(void* const* d_in, const int* in_sizes, int n_in,
                              void* d_out, int out_size, void* d_ws, size_t ws_size,
                              hipStream_t stream) {
    const float* x    = (const float*)d_in[0];
    const float* wce  = (const float*)d_in[1];
    const float* wee  = (const float*)d_in[2];
    const float* wb1  = (const float*)d_in[3];
    const float* bb1  = (const float*)d_in[4];
    const float* wb2  = (const float*)d_in[5];
    const float* bb2  = (const float*)d_in[6];
    const float* wr   = (const float*)d_in[7];
    const float* br   = (const float*)d_in[8];
    const float* wo   = (const float*)d_in[9];
    const float* bo   = (const float*)d_in[10];
    const float* wcv  = (const float*)d_in[11];
    const float* bcv  = (const float*)d_in[12];
    const int*   scale  = (const int*)d_in[13];
    const int*   scale2 = (const int*)d_in[14];
    float* out = (float*)d_out;

    float* feat     = (float*)d_ws;                        // BN*CN*HW floats (16B-aligned blocks)
    float* tblEntry = feat + (size_t)BN * CN * HW;         // 2048 floats
    unsigned short* tblM = (unsigned short*)(tblEntry + 2048);  // 16*2*4096 ushorts
    unsigned short* tblW = tblM + 16 * 2 * 4096;           // 4*9*2*64*8 ushorts
    unsigned short* xt   = tblW + 4 * 9 * 2 * 64 * 8;      // BN*HN*WN*64 ushorts

    prepass_kernel<<<TRB + 1 + TBLB, 256, 0, stream>>>(
        x, wcv, wb1, bb1, wb2, bb2, wr, br, wo, bo,
        wce, wee, scale, scale2, xt, tblW, tblEntry, tblM);
    feat_kernel<<<TRB, 256, 0, stream>>>(xt, tblW, bcv, feat);
    out_kernel<<<BN * SH * SW / 64, 256, 0, stream>>>(feat, tblEntry, tblM,
                                                      wce, wee, scale, scale2, out);
}

// Round 7
// 152.581 us; speedup vs baseline: 1.0178x; 1.0178x over previous
//
#include <hip/hip_runtime.h>
#include <hip/hip_bf16.h>
#include <math.h>

// Problem shape (fixed by setup_inputs):
//   x: [2, 64, 192, 192] fp32, scale=scale2=2 -> sh=sw=384, out: [2,64,384,384] fp32
#define BN  2
#define CN  64
#define HN  192
#define WN  192
#define SH  384
#define SW  384
#define HW  (HN * WN)
#define NPIX (BN * HN * WN)   // 73728

typedef __attribute__((ext_vector_type(8))) short bf16x8;
typedef __attribute__((ext_vector_type(4))) float f32x4;

#define CPAD  72                      // ushort stride per position ch-vector: 144B, 16B-aligned
#define TRB   (BN * HN * 3)           // 1152 transpose blocks / feat blocks
#define TBLB  64                      // table blocks in prepass

// exact round-to-nearest-even fp32 -> bf16 bits
__device__ inline unsigned short f2bf(float f) {
    unsigned int u = __float_as_uint(f);
    u += 0x7fffu + ((u >> 16) & 1u);
    return (unsigned short)(u >> 16);
}
__device__ inline unsigned int pkbf(float a, float b) {
    return (unsigned int)f2bf(a) | ((unsigned int)f2bf(b) << 16);
}
__device__ inline float bf2f(unsigned short u) {
    return __uint_as_float((unsigned int)u << 16);
}

// ---------------------------------------------------------------------------
// MLP helper: one wave, lane = hidden unit. Returns head partial sums p[6].
// ---------------------------------------------------------------------------
__device__ inline void run_mlp(int lane, float in0, float in1, float chv, float cwv,
    const float* __restrict__ wb1, const float* __restrict__ bb1,
    const float* __restrict__ wb2, const float* __restrict__ bb2,
    const float* __restrict__ wr,  const float* __restrict__ wo, float p[6])
{
    float4 w1 = ((const float4*)wb1)[lane];
    float h1 = fmaxf(bb1[lane] + w1.x * in0 + w1.y * in1 + w1.z * chv + w1.w * cwv, 0.f);
    const float4* w2row = (const float4*)(wb2 + lane * 64);
    float acc = bb2[lane];
#pragma unroll
    for (int q = 0; q < 16; ++q) {
        float4 wv = w2row[q];
        acc += wv.x * __shfl(h1, q * 4 + 0)
             + wv.y * __shfl(h1, q * 4 + 1)
             + wv.z * __shfl(h1, q * 4 + 2)
             + wv.w * __shfl(h1, q * 4 + 3);
    }
    float h2 = fmaxf(acc, 0.f);
#pragma unroll
    for (int e = 0; e < 4; ++e) p[e] = wr[e * 64 + lane] * h2;
#pragma unroll
    for (int e = 0; e < 2; ++e) p[4 + e] = wo[e * 64 + lane] * h2;
#pragma unroll
    for (int m = 1; m < 64; m <<= 1) {
#pragma unroll
        for (int e = 0; e < 6; ++e) p[e] += __shfl_xor(p[e], m);
    }
}

// ---------------------------------------------------------------------------
// Kernel 0 (v9, unchanged): prepass.
//   blocks [0, TRB):   transpose+convert x -> xt [B,H,W,C] bf16.
//   block  TRB:        precompute 9-tap A-fragments into tblW.
//   blocks > TRB:      routing/offset table + fused expert matrices.
// ---------------------------------------------------------------------------
__global__ __launch_bounds__(256) void prepass_kernel(
    const float* __restrict__ x,     // [B,64,H,W]
    const float* __restrict__ wcv,   // [64,192]
    const float* __restrict__ wb1, const float* __restrict__ bb1,
    const float* __restrict__ wb2, const float* __restrict__ bb2,
    const float* __restrict__ wr,  const float* __restrict__ br,
    const float* __restrict__ wo,  const float* __restrict__ bo,
    const float* __restrict__ wce, const float* __restrict__ wee,
    const int* __restrict__ scale_p, const int* __restrict__ scale2_p,
    unsigned short* __restrict__ xt,    // [B,H,W,64] bf16
    unsigned short* __restrict__ tblW,  // [4][9][2][64] bf16x8
    float* __restrict__ tblEntry, unsigned short* __restrict__ tblM)
{
    __shared__ __attribute__((aligned(16))) unsigned short sm[64 * CPAD]; // 9216 B

    int tid  = threadIdx.x;
    int lane = tid & 63;
    int bi = blockIdx.x;

    if (bi < TRB) {
        int jt = bi % 3;
        int t2 = bi / 3;
        int i  = t2 % HN;
        int b  = t2 / HN;
        int j0 = jt * 64;
        int w  = tid >> 6;
        int c0 = w * 16;

        const float* xp = x + (size_t)b * CN * HW + (size_t)i * WN + j0 + lane;
#pragma unroll
        for (int k = 0; k < 16; k += 2) {
            float f0 = xp[(size_t)(c0 + k) * HW];
            float f1 = xp[(size_t)(c0 + k + 1) * HW];
            *(unsigned int*)(sm + lane * CPAD + c0 + k) = pkbf(f0, f1);
        }
        __syncthreads();
        size_t obase = (((size_t)b * HN + i) * WN + j0) * 64;
#pragma unroll
        for (int it = 0; it < 2; ++it) {
            int task = tid + it * 256;       // 0..511
            int jj = task >> 3, oc = task & 7;
            uint4 v = *(const uint4*)(sm + jj * CPAD + oc * 8);
            *(uint4*)(xt + obase + (size_t)jj * 64 + oc * 8) = v;
        }
        return;
    }

    if (bi == TRB) {
        const float KXc[9] = {-1.f, 0.f, 1.f, -2.f, 0.f, 2.f, -1.f, 0.f, 1.f};
        const float KYc[9] = {-1.f, -2.f, -1.f, 0.f, 0.f, 0.f, 1.f, 2.f, 1.f};
        int wv = tid >> 6;
        int o  = (wv << 4) + (lane & 15);
        const float* wp = wcv + o * 192;
        float v0[2][8], v1[2][8], v2[2][8];
#pragma unroll
        for (int kc = 0; kc < 2; ++kc) {
            int kb = kc * 32 + (lane >> 4) * 8;
            float4 a0 = *(const float4*)(wp + kb);
            float4 a1 = *(const float4*)(wp + kb + 4);
            float4 b0 = *(const float4*)(wp + 64 + kb);
            float4 b1 = *(const float4*)(wp + 64 + kb + 4);
            float4 c0 = *(const float4*)(wp + 128 + kb);
            float4 c1 = *(const float4*)(wp + 128 + kb + 4);
            v0[kc][0]=a0.x; v0[kc][1]=a0.y; v0[kc][2]=a0.z; v0[kc][3]=a0.w;
            v0[kc][4]=a1.x; v0[kc][5]=a1.y; v0[kc][6]=a1.z; v0[kc][7]=a1.w;
            v1[kc][0]=b0.x; v1[kc][1]=b0.y; v1[kc][2]=b0.z; v1[kc][3]=b0.w;
            v1[kc][4]=b1.x; v1[kc][5]=b1.y; v1[kc][6]=b1.z; v1[kc][7]=b1.w;
            v2[kc][0]=c0.x; v2[kc][1]=c0.y; v2[kc][2]=c0.z; v2[kc][3]=c0.w;
            v2[kc][4]=c1.x; v2[kc][5]=c1.y; v2[kc][6]=c1.z; v2[kc][7]=c1.w;
        }
#pragma unroll
        for (int t = 0; t < 9; ++t) {
#pragma unroll
            for (int kc = 0; kc < 2; ++kc) {
                bf16x8 a;
#pragma unroll
                for (int e = 0; e < 8; ++e) {
                    float f = v1[kc][e] * KXc[t] + v2[kc][e] * KYc[t];
                    if (t == 4) f += v0[kc][e];
                    a[e] = (short)f2bf(f);
                }
                *(bf16x8*)(void*)(tblW + (size_t)(((wv * 9 + t) * 2 + kc) * 64 + lane) * 8) = a;
            }
        }
        return;
    }

    // ---------------- table path (LDS aliased onto sm) ---------------------
    {
        float* wcmL = (float*)sm;              // [2][512]
        float* wemL = wcmL + 1024;             // [2][512]
        float* reL  = wemL + 1024;             // [8]   (8224 B <= 9216)

        int sc = scale_p[0], sc2 = scale2_p[0];
        float scale = (float)sc, scale2 = (float)sc2;
        float in0 = 1.f / scale2, in1 = 1.f / scale;
        bool fast = (sc2 == 2 && sc <= 16);
        int tb = bi - (TRB + 1);

        if (fast) {
            int pi = tb;
            if (pi >= sc) return;
            if (tid < 64) {
                float ih = (pi + 0.5f) / scale;
                float chv = ih - floorf(ih + 0.001f) - 0.5f;
                float p0[6], p1[6];
                {
                    float iw = 0.5f / scale2;
                    float cwv = iw - floorf(iw + 0.001f) - 0.5f;
                    run_mlp(lane, in0, in1, chv, cwv, wb1, bb1, wb2, bb2, wr, wo, p0);
                }
                {
                    float iw = 1.5f / scale2;
                    float cwv = iw - floorf(iw + 0.001f) - 0.5f;
                    run_mlp(lane, in0, in1, chv, cwv, wb1, bb1, wb2, bb2, wr, wo, p1);
                }
                if (lane == 0) {
                    float* t0 = tblEntry + (pi * 2 + 0) * 8;
                    float* t1 = tblEntry + (pi * 2 + 1) * 8;
#pragma unroll
                    for (int e = 0; e < 4; ++e) {
                        float rE = 1.f / (1.f + expf(-(p0[e] + br[e])));
                        float rO = 1.f / (1.f + expf(-(p1[e] + br[e])));
                        t0[e] = rE; t1[e] = rO;
                        reL[e] = rE; reL[4 + e] = rO;
                    }
                    t0[4] = p0[4] + bo[0]; t0[5] = p0[5] + bo[1];
                    t1[4] = p1[4] + bo[0]; t1[5] = p1[5] + bo[1];
                }
            }
            __syncthreads();
            float reE0 = reL[0], reE1 = reL[1], reE2 = reL[2], reE3 = reL[3];
            float reO0 = reL[4], reO1 = reL[5], reO2 = reL[6], reO3 = reL[7];
            for (int idx = tid; idx < 512; idx += 256) {
                float a = wce[idx], bq = wce[512 + idx], c = wce[1024 + idx], d = wce[1536 + idx];
                wcmL[idx]       = reE0 * a + reE1 * bq + reE2 * c + reE3 * d;
                wcmL[512 + idx] = reO0 * a + reO1 * bq + reO2 * c + reO3 * d;
                float e_ = wee[idx], f = wee[512 + idx], g = wee[1024 + idx], h = wee[1536 + idx];
                wemL[idx]       = reE0 * e_ + reE1 * f + reE2 * g + reE3 * h;
                wemL[512 + idx] = reO0 * e_ + reO1 * f + reO2 * g + reO3 * h;
            }
            __syncthreads();
            int co  = tid >> 2;
            int ci0 = (tid & 3) << 4;
            float w0[8], w1[8];
#pragma unroll
            for (int k = 0; k < 8; ++k) {
                w0[k] = wemL[co * 8 + k];
                w1[k] = wemL[512 + co * 8 + k];
            }
            unsigned short* tbp = tblM + (size_t)pi * 2 * 4096;
#pragma unroll
            for (int cc = 0; cc < 16; ++cc) {
                int ci = ci0 + cc;
                float m0 = 0.f, m1 = 0.f;
#pragma unroll
                for (int k = 0; k < 8; ++k) {
                    m0 += w0[k] * wcmL[k * 64 + ci];
                    m1 += w1[k] * wcmL[512 + k * 64 + ci];
                }
                tbp[co * 64 + ci]        = f2bf(0.5f * (m0 + m1));   // Mavg
                tbp[4096 + co * 64 + ci] = f2bf(0.5f * (m0 - m1));   // Mdiff
            }
        } else {
            int w_ = (tb * 256 + tid) >> 6;
            if (w_ >= sc * sc2) return;
            int pi = w_ / sc2, pj = w_ - pi * sc2;
            float ih = (pi + 0.5f) / scale;
            float chv = ih - floorf(ih + 0.001f) - 0.5f;
            float iw = (pj + 0.5f) / scale2;
            float cwv = iw - floorf(iw + 0.001f) - 0.5f;
            float p[6];
            run_mlp(lane, in0, in1, chv, cwv, wb1, bb1, wb2, bb2, wr, wo, p);
            if (lane == 0) {
                float* tp = tblEntry + w_ * 8;
#pragma unroll
                for (int e = 0; e < 4; ++e) tp[e] = 1.f / (1.f + expf(-(p[e] + br[e])));
                tp[4] = p[4] + bo[0];
                tp[5] = p[5] + bo[1];
            }
        }
    }
}

// ---------------------------------------------------------------------------
// Kernel 1 (v10): feat 3x3-conv MFMA GEMM -> featN [B,H,W,64] bf16.
//   v9 post-mortem: totals tracked the MEMORY floor, not the schedule; the
//   fp32 NCHW feat round-trip (75.5 MB write + 75.5 MB scattered read) was
//   the dominant remaining term. v10 stores feat as NHWC bf16 (37.7 MB) via
//   an LDS re-tile for coalesced b128 stores. GEMM/staging unchanged from v9.
// ---------------------------------------------------------------------------
__global__ __launch_bounds__(256) void feat_kernel(
    const unsigned short* __restrict__ xt,    // [B,H,W,64] bf16
    const unsigned short* __restrict__ tblW,  // [4][9][2][64] bf16x8
    const float* __restrict__ bcv,            // [64]
    unsigned short* __restrict__ featN)       // [B,H,W,64] bf16
{
    __shared__ __attribute__((aligned(16))) unsigned short sm[198 * CPAD]; // 28512 B

    int tid  = threadIdx.x;
    int lane = tid & 63;
    int bi = blockIdx.x;
    int jt = bi % 3;
    int t2 = bi / 3;
    int i0 = t2 % HN;
    int b  = t2 / HN;
    int j0 = jt * 64;
    int w  = __builtin_amdgcn_readfirstlane(tid >> 6);

    int row = lane & 15;
    int q   = lane >> 4;

    // ---- A fragments: 18 coalesced b128 loads (precomputed taps) ----
    bf16x8 afrag[9][2];
#pragma unroll
    for (int t = 0; t < 9; ++t)
#pragma unroll
        for (int kc = 0; kc < 2; ++kc)
            afrag[t][kc] = *(const bf16x8*)(void*)(
                tblW + (size_t)(((w * 9 + t) * 2 + kc) * 64 + lane) * 8);

    // ---- stage x tile: 1584 (pos, ch-octet) tasks, 7 iters ----
#pragma unroll
    for (int it = 0; it < 7; ++it) {
        int task = tid + it * 256;
        if (task < 198 * 8) {
            int p  = task >> 3;
            int oc = task & 7;
            int rowi = p / 66;
            int col  = p - rowi * 66;
            int sr = i0 - 1 + rowi;
            int hc = j0 - 1 + col;
            bool ok = (sr >= 0) && (sr < HN) && (hc >= 0) && (hc < WN);
            int srb = ok ? sr : 0;
            int hcb = ok ? hc : 0;
            uint4 v = *(const uint4*)(xt + (((size_t)b * HN + srb) * WN + hcb) * 64 + oc * 8);
            if (!ok) v = (uint4){0u, 0u, 0u, 0u};
            *(uint4*)(sm + p * CPAD + oc * 8) = v;
        }
    }

    __syncthreads();

    // ---- MFMA: 4 n-subtiles x 9 taps x 2 k-chunks = 72 ----
    f32x4 acc[4] = {};
    const unsigned short* bb0 = sm + row * CPAD + (q << 3);
#pragma unroll
    for (int nt = 0; nt < 4; ++nt) {
#pragma unroll
        for (int t = 0; t < 9; ++t) {
            int a_ = t / 3, dxi = t - a_ * 3;
#pragma unroll
            for (int kc = 0; kc < 2; ++kc) {
                bf16x8 bv = *(const bf16x8*)(bb0 + (a_ * 66 + nt * 16 + dxi) * CPAD + kc * 32);
                acc[nt] = __builtin_amdgcn_mfma_f32_16x16x32_bf16(afrag[t][kc], bv, acc[nt], 0, 0, 0);
            }
        }
    }

    // ---- epilogue: bias, bf16-pack to LDS, coalesced NHWC store ----
    __syncthreads();   // all waves done reading sm before overwrite
    {
        int oc0 = (w << 4) + (q << 2);
        float b0 = bcv[oc0], b1 = bcv[oc0 + 1], b2 = bcv[oc0 + 2], b3 = bcv[oc0 + 3];
#pragma unroll
        for (int nt = 0; nt < 4; ++nt) {
            int px = nt * 16 + row;
            uint2 uu;
            uu.x = pkbf(acc[nt][0] + b0, acc[nt][1] + b1);
            uu.y = pkbf(acc[nt][2] + b2, acc[nt][3] + b3);
            *(uint2*)(sm + px * CPAD + oc0) = uu;
        }
    }
    __syncthreads();
    {
        size_t obase = ((size_t)b * HN + i0) * WN + j0;
#pragma unroll
        for (int it = 0; it < 2; ++it) {
            int task = tid + it * 256;       // 0..511
            int px = task >> 3, oc = task & 7;
            uint4 v = *(const uint4*)(sm + px * CPAD + oc * 8);
            *(uint4*)(featN + (obase + px) * 64 + oc * 8) = v;
        }
    }
}

// ---------------------------------------------------------------------------
// Kernel 2 (v5): NHWC-bf16 bilinear gather + fused expert GEMM + residual.
//   v4 gathered 64 scattered NCHW dwords/lane. v5: wave0 precomputes per-px
//   clamped corner indices + masked weights; 512 (px, ch-octet) tasks each do
//   4 contiguous b128 corner loads + 32 FMA (fp32 accum for exact residual).
// ---------------------------------------------------------------------------
#define BKP 72   // ushort stride of Bsv rows
#define FPAD 68  // float stride of fea32 rows (16B-aligned octets)
__global__ __launch_bounds__(256) void out_kernel(
    const unsigned short* __restrict__ featN,  // [B,H,W,64] bf16
    const float* __restrict__ tblEntry,        // [256][8]
    const unsigned short* __restrict__ tblM,   // [pi][2][64][64] bf16
    const float* __restrict__ wce,             // [4,8,64]
    const float* __restrict__ wee,             // [4,64,8]
    const int* __restrict__ scale_p, const int* __restrict__ scale2_p,
    float* __restrict__ out)                   // [B,64,SH,SW]
{
    __shared__ __attribute__((aligned(16))) float fea32[64 * FPAD];   // 17408 B
    __shared__ __attribute__((aligned(16))) unsigned short Bsv[64 * BKP]; // 9216 B
    __shared__ int   cidx[4 * 64];
    __shared__ float cwt[4 * 64];
    float* midp = fea32;                       // generic-path alias

    int Bk = blockIdx.x;
    int T = gridDim.x;                         // 4608, %8==0
    int t = ((T & 7) == 0) ? ((Bk & 7) * (T >> 3) + (Bk >> 3)) : Bk;

    int tid = threadIdx.x;
    int g = __builtin_amdgcn_readfirstlane(tid >> 6);
    int lane = tid & 63;
    int pix0 = t * 64;
    int b = pix0 / (SH * SW);
    int r0 = pix0 - b * SH * SW;
    int i = r0 / SW;
    int j0 = r0 - i * SW;

    int sc = scale_p[0], sc2 = scale2_p[0];
    float scale = (float)sc, scale2 = (float)sc2;
    int pi = i - (i / sc) * sc;                // wave-uniform
    const float inv_wm1 = 2.f / (float)(WN - 1);
    const float inv_hm1 = 2.f / (float)(HN - 1);

    bool fast = (sc2 == 2 && sc <= 16);
    if (fast) {
        // ---- wave0: per-pixel corner indices + masked weights -> LDS ----
        if (tid < 64) {
            int px = tid;
            int jpx = j0 + px;
            int pjx = jpx - (jpx / sc2) * sc2;
            int entry = pi * sc2 + pjx;
            float offx = tblEntry[entry * 8 + 4];
            float offy = tblEntry[entry * 8 + 5];
            float gx = ((jpx + 0.5f) / scale2 - 0.5f) * inv_wm1 - 1.f + offx * inv_wm1;
            float gy = ((i + 0.5f) / scale  - 0.5f) * inv_hm1 - 1.f + offy * inv_hm1;
            float ix = ((gx + 1.f) * WN - 1.f) * 0.5f;
            float iy = ((gy + 1.f) * HN - 1.f) * 0.5f;
            float fx0 = floorf(ix), fy0 = floorf(iy);
            int x0 = (int)fx0, y0 = (int)fy0;
            float wx1 = ix - fx0, wx0 = 1.f - wx1;
            float wy1 = iy - fy0, wy0 = 1.f - wy1;
            bool vx0 = (x0 >= 0) && (x0 <= WN - 1);
            bool vx1 = (x0 + 1 >= 0) && (x0 + 1 <= WN - 1);
            bool vy0 = (y0 >= 0) && (y0 <= HN - 1);
            bool vy1 = (y0 + 1 >= 0) && (y0 + 1 <= HN - 1);
            int x0c = min(max(x0, 0), WN - 1);
            int x1c = min(max(x0 + 1, 0), WN - 1);
            int y0c = min(max(y0, 0), HN - 1);
            int y1c = min(max(y0 + 1, 0), HN - 1);
            cidx[0 * 64 + px] = y0c * WN + x0c;
            cidx[1 * 64 + px] = y0c * WN + x1c;
            cidx[2 * 64 + px] = y1c * WN + x0c;
            cidx[3 * 64 + px] = y1c * WN + x1c;
            cwt[0 * 64 + px] = wx0 * wy0 * ((vx0 && vy0) ? 1.f : 0.f);
            cwt[1 * 64 + px] = wx1 * wy0 * ((vx1 && vy0) ? 1.f : 0.f);
            cwt[2 * 64 + px] = wx0 * wy1 * ((vx0 && vy1) ? 1.f : 0.f);
            cwt[3 * 64 + px] = wx1 * wy1 * ((vx1 && vy1) ? 1.f : 0.f);
        }

        // ---- A fragments (global, issue before barrier): Mavg/Mdiff rows ----
        int row = lane & 15;
        int kb  = (lane >> 4) << 3;
        const unsigned short* Mb = tblM + (size_t)pi * 2 * 4096 + (g * 16 + row) * 64 + kb;
        bf16x8 a1[2], a2[2];
        a1[0] = *(const bf16x8*)(Mb);
        a1[1] = *(const bf16x8*)(Mb + 32);
        a2[0] = *(const bf16x8*)(Mb + 4096);
        a2[1] = *(const bf16x8*)(Mb + 4096 + 32);

        __syncthreads();

        // ---- gather: 512 (px, ch-octet) tasks, 4 contiguous b128 each ----
        const unsigned short* fb = featN + (size_t)b * HW * 64;
#pragma unroll
        for (int it = 0; it < 2; ++it) {
            int task = tid + it * 256;
            int px = task >> 3, oct = task & 7;
            const unsigned short* fo = fb + oct * 8;
            float a8[8] = {};
#pragma unroll
            for (int k = 0; k < 4; ++k) {
                bf16x8 cv = *(const bf16x8*)(fo + (size_t)cidx[k * 64 + px] * 64);
                float wk = cwt[k * 64 + px];
#pragma unroll
                for (int e = 0; e < 8; ++e)
                    a8[e] += wk * bf2f((unsigned short)cv[e]);
            }
            float4 lo = {a8[0], a8[1], a8[2], a8[3]};
            float4 hi = {a8[4], a8[5], a8[6], a8[7]};
            *(float4*)(fea32 + px * FPAD + oct * 8)     = lo;
            *(float4*)(fea32 + px * FPAD + oct * 8 + 4) = hi;
            uint4 pk;
            pk.x = pkbf(a8[0], a8[1]);
            pk.y = pkbf(a8[2], a8[3]);
            pk.z = pkbf(a8[4], a8[5]);
            pk.w = pkbf(a8[6], a8[7]);
            *(uint4*)(Bsv + px * BKP + oct * 8) = pk;
        }

        __syncthreads();

        // ---- MFMA: D1 = Mavg@fea0, D2 = Mdiff@fea0 (M=16/wave, N=64, K=64) ----
        f32x4 acc1[4] = {}, acc2[4] = {};
        const unsigned short* bp = Bsv + (lane & 15) * BKP + kb;
#pragma unroll
        for (int nt = 0; nt < 4; ++nt) {
            const unsigned short* bnt = bp + nt * 16 * BKP;
#pragma unroll
            for (int ks = 0; ks < 2; ++ks) {
                bf16x8 bf = *(const bf16x8*)(bnt + ks * 32);
                acc1[nt] = __builtin_amdgcn_mfma_f32_16x16x32_bf16(a1[ks], bf, acc1[nt], 0, 0, 0);
                acc2[nt] = __builtin_amdgcn_mfma_f32_16x16x32_bf16(a2[ks], bf, acc2[nt], 0, 0, 0);
            }
        }

        // ---- epilogue: residual (fp32 LDS) + parity sign, store ----
        int q = lane >> 4;
#pragma unroll
        for (int rr = 0; rr < 4; ++rr) {
            int c = g * 16 + q * 4 + rr;
            size_t rowb = (size_t)(b * CN + c) * SH * SW + r0;
#pragma unroll
            for (int nt = 0; nt < 4; ++nt) {
                int n = (lane & 15) + nt * 16;
                float sgn = (n & 1) ? -1.f : 1.f;
                float v = fea32[n * FPAD + c] + acc1[nt][rr] + sgn * acc2[nt][rr];
                out[rowb + n] = v;
            }
        }
    } else {
        // ---- generic path (not exercised at scale=2): NHWC scalar gather ----
        int j = j0 + lane;
        int r = r0 + lane;
        int pj = j - (j / sc2) * sc2;
        int entry = pi * sc2 + pj;
        float offx = tblEntry[entry * 8 + 4];
        float offy = tblEntry[entry * 8 + 5];
        float gx = ((j + 0.5f) / scale2 - 0.5f) * inv_wm1 - 1.f + offx * inv_wm1;
        float gy = ((i + 0.5f) / scale  - 0.5f) * inv_hm1 - 1.f + offy * inv_hm1;
        float ix = ((gx + 1.f) * WN - 1.f) * 0.5f;
        float iy = ((gy + 1.f) * HN - 1.f) * 0.5f;
        float fx0 = floorf(ix), fy0 = floorf(iy);
        int x0 = (int)fx0, y0 = (int)fy0;
        float wx1 = ix - fx0, wx0 = 1.f - wx1;
        float wy1 = iy - fy0, wy0 = 1.f - wy1;
        bool vx0 = (x0 >= 0) && (x0 <= WN - 1);
        bool vx1 = (x0 + 1 >= 0) && (x0 + 1 <= WN - 1);
        bool vy0 = (y0 >= 0) && (y0 <= HN - 1);
        bool vy1 = (y0 + 1 >= 0) && (y0 + 1 <= HN - 1);
        int x0c = min(max(x0, 0), WN - 1);
        int x1c = min(max(x0 + 1, 0), WN - 1);
        int y0c = min(max(y0, 0), HN - 1);
        int y1c = min(max(y0 + 1, 0), HN - 1);
        float w00 = wx0 * wy0 * ((vx0 && vy0) ? 1.f : 0.f);
        float w10 = wx1 * wy0 * ((vx1 && vy0) ? 1.f : 0.f);
        float w01 = wx0 * wy1 * ((vx0 && vy1) ? 1.f : 0.f);
        float w11 = wx1 * wy1 * ((vx1 && vy1) ? 1.f : 0.f);
        const unsigned short* fb = featN + ((size_t)b * HW) * 64;
        const unsigned short* p00 = fb + (size_t)(y0c * WN + x0c) * 64;
        const unsigned short* p10 = fb + (size_t)(y0c * WN + x1c) * 64;
        const unsigned short* p01 = fb + (size_t)(y1c * WN + x0c) * 64;
        const unsigned short* p11 = fb + (size_t)(y1c * WN + x1c) * 64;

        float f0[16];
#pragma unroll
        for (int cc = 0; cc < 16; ++cc) {
            int c = g * 16 + cc;
            f0[cc] = bf2f(p00[c]) * w00 + bf2f(p10[c]) * w10
                   + bf2f(p01[c]) * w01 + bf2f(p11[c]) * w11;
        }

        float4 rw = *(const float4*)(tblEntry + entry * 8);
        float re[4] = {rw.x, rw.y, rw.z, rw.w};
        float part[4][8];
#pragma unroll
        for (int e = 0; e < 4; ++e) {
#pragma unroll
            for (int k = 0; k < 8; ++k) {
                const float* wrow = wce + (e * 8 + k) * 64 + g * 16;
                float d = 0.f;
#pragma unroll
                for (int cc = 0; cc < 16; ++cc) d += wrow[cc] * f0[cc];
                part[e][k] = d;
            }
        }
#pragma unroll
        for (int k = 0; k < 8; ++k) {
            float m = re[0] * part[0][k] + re[1] * part[1][k]
                    + re[2] * part[2][k] + re[3] * part[3][k];
            midp[(g * 64 + lane) * 9 + k] = m;
        }
        __syncthreads();
        float mid[8];
#pragma unroll
        for (int k = 0; k < 8; ++k)
            mid[k] = midp[(0 * 64 + lane) * 9 + k] + midp[(1 * 64 + lane) * 9 + k]
                   + midp[(2 * 64 + lane) * 9 + k] + midp[(3 * 64 + lane) * 9 + k];
#pragma unroll
        for (int cc = 0; cc < 16; ++cc) {
            int c = g * 16 + cc;
            float v = f0[cc];
#pragma unroll
            for (int e = 0; e < 4; ++e) {
                const float* wrow = wee + (e * 64 + c) * 8;
                float d = 0.f;
#pragma unroll
                for (int k = 0; k < 8; ++k) d += wrow[k] * mid[k];
                v += re[e] * d;
            }
            out[(size_t)(b * CN + c) * SH * SW + r] = v;
        }
    }
}

extern "C" void kernel_launch(void* const* d_in, const int* in_sizes, int n_in,
                              void* d_out, int out_size, void* d_ws, size_t ws_size,
                              hipStream_t stream) {
    const float* x    = (const float*)d_in[0];
    const float* wce  = (const float*)d_in[1];
    const float* wee  = (const float*)d_in[2];
    const float* wb1  = (const float*)d_in[3];
    const float* bb1  = (const float*)d_in[4];
    const float* wb2  = (const float*)d_in[5];
    const float* bb2  = (const float*)d_in[6];
    const float* wr   = (const float*)d_in[7];
    const float* br   = (const float*)d_in[8];
    const float* wo   = (const float*)d_in[9];
    const float* bo   = (const float*)d_in[10];
    const float* wcv  = (const float*)d_in[11];
    const float* bcv  = (const float*)d_in[12];
    const int*   scale  = (const int*)d_in[13];
    const int*   scale2 = (const int*)d_in[14];
    float* out = (float*)d_out;

    // workspace layout (16B-aligned chunks)
    unsigned short* featN = (unsigned short*)d_ws;                  // BN*HW*64 bf16 = 9.44 MB
    float* tblEntry = (float*)((char*)d_ws + (size_t)BN * HW * 64 * 2);   // 8 KB
    unsigned short* tblM = (unsigned short*)((char*)tblEntry + 2048 * 4); // 256 KB
    unsigned short* tblW = tblM + 16 * 2 * 4096;                    // 72 KB
    unsigned short* xt   = tblW + 4 * 9 * 2 * 64 * 8;               // 9.44 MB

    prepass_kernel<<<TRB + 1 + TBLB, 256, 0, stream>>>(
        x, wcv, wb1, bb1, wb2, bb2, wr, br, wo, bo,
        wce, wee, scale, scale2, xt, tblW, tblEntry, tblM);
    feat_kernel<<<TRB, 256, 0, stream>>>(xt, tblW, bcv, featN);
    out_kernel<<<BN * SH * SW / 64, 256, 0, stream>>>(featN, tblEntry, tblM,
                                                      wce, wee, scale, scale2, out);
}

// Round 8
// 152.027 us; speedup vs baseline: 1.0215x; 1.0036x over previous
//
#include <hip/hip_runtime.h>
#include <hip/hip_bf16.h>
#include <math.h>

// Problem shape (fixed by setup_inputs):
//   x: [2, 64, 192, 192] fp32, scale=scale2=2 -> sh=sw=384, out: [2,64,384,384] fp32
#define BN  2
#define CN  64
#define HN  192
#define WN  192
#define SH  384
#define SW  384
#define HW  (HN * WN)
#define NPIX (BN * HN * WN)   // 73728

typedef __attribute__((ext_vector_type(8))) short bf16x8;
typedef __attribute__((ext_vector_type(4))) float f32x4;

#define CPAD  72                      // ushort stride per position ch-vector: 144B, 16B-aligned
#define TRB   (BN * HN * 3)           // 1152 transpose blocks / feat blocks
#define TBLB  64                      // table blocks in prepass

// exact round-to-nearest-even fp32 -> bf16 bits
__device__ inline unsigned short f2bf(float f) {
    unsigned int u = __float_as_uint(f);
    u += 0x7fffu + ((u >> 16) & 1u);
    return (unsigned short)(u >> 16);
}
__device__ inline unsigned int pkbf(float a, float b) {
    return (unsigned int)f2bf(a) | ((unsigned int)f2bf(b) << 16);
}
__device__ inline float bf2f(unsigned short u) {
    return __uint_as_float((unsigned int)u << 16);
}

// ---------------------------------------------------------------------------
// MLP helper: one wave, lane = hidden unit. Returns head partial sums p[6].
// ---------------------------------------------------------------------------
__device__ inline void run_mlp(int lane, float in0, float in1, float chv, float cwv,
    const float* __restrict__ wb1, const float* __restrict__ bb1,
    const float* __restrict__ wb2, const float* __restrict__ bb2,
    const float* __restrict__ wr,  const float* __restrict__ wo, float p[6])
{
    float4 w1 = ((const float4*)wb1)[lane];
    float h1 = fmaxf(bb1[lane] + w1.x * in0 + w1.y * in1 + w1.z * chv + w1.w * cwv, 0.f);
    const float4* w2row = (const float4*)(wb2 + lane * 64);
    float acc = bb2[lane];
#pragma unroll
    for (int q = 0; q < 16; ++q) {
        float4 wv = w2row[q];
        acc += wv.x * __shfl(h1, q * 4 + 0)
             + wv.y * __shfl(h1, q * 4 + 1)
             + wv.z * __shfl(h1, q * 4 + 2)
             + wv.w * __shfl(h1, q * 4 + 3);
    }
    float h2 = fmaxf(acc, 0.f);
#pragma unroll
    for (int e = 0; e < 4; ++e) p[e] = wr[e * 64 + lane] * h2;
#pragma unroll
    for (int e = 0; e < 2; ++e) p[4 + e] = wo[e * 64 + lane] * h2;
#pragma unroll
    for (int m = 1; m < 64; m <<= 1) {
#pragma unroll
        for (int e = 0; e < 6; ++e) p[e] += __shfl_xor(p[e], m);
    }
}

// ---------------------------------------------------------------------------
// Kernel 0 (v11): prepass.
//   blocks [0, TRB):   transpose+convert x -> xt [B,H,W,C] bf16.
//   block  TRB:        precompute 9-tap A-fragments into tblW.
//   blocks > TRB:      routing/offset table + fused expert matrices.
//   v11 change: Mavg gets +IDENTITY (out = (I+M)@fea0 -> out_kernel needs no
//   fp32 residual path). Exact 1.0 in bf16; Mdiff unchanged.
// ---------------------------------------------------------------------------
__global__ __launch_bounds__(256) void prepass_kernel(
    const float* __restrict__ x,     // [B,64,H,W]
    const float* __restrict__ wcv,   // [64,192]
    const float* __restrict__ wb1, const float* __restrict__ bb1,
    const float* __restrict__ wb2, const float* __restrict__ bb2,
    const float* __restrict__ wr,  const float* __restrict__ br,
    const float* __restrict__ wo,  const float* __restrict__ bo,
    const float* __restrict__ wce, const float* __restrict__ wee,
    const int* __restrict__ scale_p, const int* __restrict__ scale2_p,
    unsigned short* __restrict__ xt,    // [B,H,W,64] bf16
    unsigned short* __restrict__ tblW,  // [4][9][2][64] bf16x8
    float* __restrict__ tblEntry, unsigned short* __restrict__ tblM)
{
    __shared__ __attribute__((aligned(16))) unsigned short sm[64 * CPAD]; // 9216 B

    int tid  = threadIdx.x;
    int lane = tid & 63;
    int bi = blockIdx.x;

    if (bi < TRB) {
        int jt = bi % 3;
        int t2 = bi / 3;
        int i  = t2 % HN;
        int b  = t2 / HN;
        int j0 = jt * 64;
        int w  = tid >> 6;
        int c0 = w * 16;

        const float* xp = x + (size_t)b * CN * HW + (size_t)i * WN + j0 + lane;
#pragma unroll
        for (int k = 0; k < 16; k += 2) {
            float f0 = xp[(size_t)(c0 + k) * HW];
            float f1 = xp[(size_t)(c0 + k + 1) * HW];
            *(unsigned int*)(sm + lane * CPAD + c0 + k) = pkbf(f0, f1);
        }
        __syncthreads();
        size_t obase = (((size_t)b * HN + i) * WN + j0) * 64;
#pragma unroll
        for (int it = 0; it < 2; ++it) {
            int task = tid + it * 256;       // 0..511
            int jj = task >> 3, oc = task & 7;
            uint4 v = *(const uint4*)(sm + jj * CPAD + oc * 8);
            *(uint4*)(xt + obase + (size_t)jj * 64 + oc * 8) = v;
        }
        return;
    }

    if (bi == TRB) {
        const float KXc[9] = {-1.f, 0.f, 1.f, -2.f, 0.f, 2.f, -1.f, 0.f, 1.f};
        const float KYc[9] = {-1.f, -2.f, -1.f, 0.f, 0.f, 0.f, 1.f, 2.f, 1.f};
        int wv = tid >> 6;
        int o  = (wv << 4) + (lane & 15);
        const float* wp = wcv + o * 192;
        float v0[2][8], v1[2][8], v2[2][8];
#pragma unroll
        for (int kc = 0; kc < 2; ++kc) {
            int kb = kc * 32 + (lane >> 4) * 8;
            float4 a0 = *(const float4*)(wp + kb);
            float4 a1 = *(const float4*)(wp + kb + 4);
            float4 b0 = *(const float4*)(wp + 64 + kb);
            float4 b1 = *(const float4*)(wp + 64 + kb + 4);
            float4 c0 = *(const float4*)(wp + 128 + kb);
            float4 c1 = *(const float4*)(wp + 128 + kb + 4);
            v0[kc][0]=a0.x; v0[kc][1]=a0.y; v0[kc][2]=a0.z; v0[kc][3]=a0.w;
            v0[kc][4]=a1.x; v0[kc][5]=a1.y; v0[kc][6]=a1.z; v0[kc][7]=a1.w;
            v1[kc][0]=b0.x; v1[kc][1]=b0.y; v1[kc][2]=b0.z; v1[kc][3]=b0.w;
            v1[kc][4]=b1.x; v1[kc][5]=b1.y; v1[kc][6]=b1.z; v1[kc][7]=b1.w;
            v2[kc][0]=c0.x; v2[kc][1]=c0.y; v2[kc][2]=c0.z; v2[kc][3]=c0.w;
            v2[kc][4]=c1.x; v2[kc][5]=c1.y; v2[kc][6]=c1.z; v2[kc][7]=c1.w;
        }
#pragma unroll
        for (int t = 0; t < 9; ++t) {
#pragma unroll
            for (int kc = 0; kc < 2; ++kc) {
                bf16x8 a;
#pragma unroll
                for (int e = 0; e < 8; ++e) {
                    float f = v1[kc][e] * KXc[t] + v2[kc][e] * KYc[t];
                    if (t == 4) f += v0[kc][e];
                    a[e] = (short)f2bf(f);
                }
                *(bf16x8*)(void*)(tblW + (size_t)(((wv * 9 + t) * 2 + kc) * 64 + lane) * 8) = a;
            }
        }
        return;
    }

    // ---------------- table path (LDS aliased onto sm) ---------------------
    {
        float* wcmL = (float*)sm;              // [2][512]
        float* wemL = wcmL + 1024;             // [2][512]
        float* reL  = wemL + 1024;             // [8]   (8224 B <= 9216)

        int sc = scale_p[0], sc2 = scale2_p[0];
        float scale = (float)sc, scale2 = (float)sc2;
        float in0 = 1.f / scale2, in1 = 1.f / scale;
        bool fast = (sc2 == 2 && sc <= 16);
        int tb = bi - (TRB + 1);

        if (fast) {
            int pi = tb;
            if (pi >= sc) return;
            if (tid < 64) {
                float ih = (pi + 0.5f) / scale;
                float chv = ih - floorf(ih + 0.001f) - 0.5f;
                float p0[6], p1[6];
                {
                    float iw = 0.5f / scale2;
                    float cwv = iw - floorf(iw + 0.001f) - 0.5f;
                    run_mlp(lane, in0, in1, chv, cwv, wb1, bb1, wb2, bb2, wr, wo, p0);
                }
                {
                    float iw = 1.5f / scale2;
                    float cwv = iw - floorf(iw + 0.001f) - 0.5f;
                    run_mlp(lane, in0, in1, chv, cwv, wb1, bb1, wb2, bb2, wr, wo, p1);
                }
                if (lane == 0) {
                    float* t0 = tblEntry + (pi * 2 + 0) * 8;
                    float* t1 = tblEntry + (pi * 2 + 1) * 8;
#pragma unroll
                    for (int e = 0; e < 4; ++e) {
                        float rE = 1.f / (1.f + expf(-(p0[e] + br[e])));
                        float rO = 1.f / (1.f + expf(-(p1[e] + br[e])));
                        t0[e] = rE; t1[e] = rO;
                        reL[e] = rE; reL[4 + e] = rO;
                    }
                    t0[4] = p0[4] + bo[0]; t0[5] = p0[5] + bo[1];
                    t1[4] = p1[4] + bo[0]; t1[5] = p1[5] + bo[1];
                }
            }
            __syncthreads();
            float reE0 = reL[0], reE1 = reL[1], reE2 = reL[2], reE3 = reL[3];
            float reO0 = reL[4], reO1 = reL[5], reO2 = reL[6], reO3 = reL[7];
            for (int idx = tid; idx < 512; idx += 256) {
                float a = wce[idx], bq = wce[512 + idx], c = wce[1024 + idx], d = wce[1536 + idx];
                wcmL[idx]       = reE0 * a + reE1 * bq + reE2 * c + reE3 * d;
                wcmL[512 + idx] = reO0 * a + reO1 * bq + reO2 * c + reO3 * d;
                float e_ = wee[idx], f = wee[512 + idx], g = wee[1024 + idx], h = wee[1536 + idx];
                wemL[idx]       = reE0 * e_ + reE1 * f + reE2 * g + reE3 * h;
                wemL[512 + idx] = reO0 * e_ + reO1 * f + reO2 * g + reO3 * h;
            }
            __syncthreads();
            int co  = tid >> 2;
            int ci0 = (tid & 3) << 4;
            float w0[8], w1[8];
#pragma unroll
            for (int k = 0; k < 8; ++k) {
                w0[k] = wemL[co * 8 + k];
                w1[k] = wemL[512 + co * 8 + k];
            }
            unsigned short* tbp = tblM + (size_t)pi * 2 * 4096;
#pragma unroll
            for (int cc = 0; cc < 16; ++cc) {
                int ci = ci0 + cc;
                float m0 = 0.f, m1 = 0.f;
#pragma unroll
                for (int k = 0; k < 8; ++k) {
                    m0 += w0[k] * wcmL[k * 64 + ci];
                    m1 += w1[k] * wcmL[512 + k * 64 + ci];
                }
                float avg = 0.5f * (m0 + m1) + ((co == ci) ? 1.f : 0.f);  // identity fold
                tbp[co * 64 + ci]        = f2bf(avg);                     // Mavg + I
                tbp[4096 + co * 64 + ci] = f2bf(0.5f * (m0 - m1));        // Mdiff
            }
        } else {
            int w_ = (tb * 256 + tid) >> 6;
            if (w_ >= sc * sc2) return;
            int pi = w_ / sc2, pj = w_ - pi * sc2;
            float ih = (pi + 0.5f) / scale;
            float chv = ih - floorf(ih + 0.001f) - 0.5f;
            float iw = (pj + 0.5f) / scale2;
            float cwv = iw - floorf(iw + 0.001f) - 0.5f;
            float p[6];
            run_mlp(lane, in0, in1, chv, cwv, wb1, bb1, wb2, bb2, wr, wo, p);
            if (lane == 0) {
                float* tp = tblEntry + w_ * 8;
#pragma unroll
                for (int e = 0; e < 4; ++e) tp[e] = 1.f / (1.f + expf(-(p[e] + br[e])));
                tp[4] = p[4] + bo[0];
                tp[5] = p[5] + bo[1];
            }
        }
    }
}

// ---------------------------------------------------------------------------
// Kernel 1 (v10, unchanged): feat 3x3-conv MFMA GEMM -> featN [B,H,W,64] bf16.
// ---------------------------------------------------------------------------
__global__ __launch_bounds__(256) void feat_kernel(
    const unsigned short* __restrict__ xt,    // [B,H,W,64] bf16
    const unsigned short* __restrict__ tblW,  // [4][9][2][64] bf16x8
    const float* __restrict__ bcv,            // [64]
    unsigned short* __restrict__ featN)       // [B,H,W,64] bf16
{
    __shared__ __attribute__((aligned(16))) unsigned short sm[198 * CPAD]; // 28512 B

    int tid  = threadIdx.x;
    int lane = tid & 63;
    int bi = blockIdx.x;
    int jt = bi % 3;
    int t2 = bi / 3;
    int i0 = t2 % HN;
    int b  = t2 / HN;
    int j0 = jt * 64;
    int w  = __builtin_amdgcn_readfirstlane(tid >> 6);

    int row = lane & 15;
    int q   = lane >> 4;

    // ---- A fragments: 18 coalesced b128 loads (precomputed taps) ----
    bf16x8 afrag[9][2];
#pragma unroll
    for (int t = 0; t < 9; ++t)
#pragma unroll
        for (int kc = 0; kc < 2; ++kc)
            afrag[t][kc] = *(const bf16x8*)(void*)(
                tblW + (size_t)(((w * 9 + t) * 2 + kc) * 64 + lane) * 8);

    // ---- stage x tile: 1584 (pos, ch-octet) tasks, 7 iters ----
#pragma unroll
    for (int it = 0; it < 7; ++it) {
        int task = tid + it * 256;
        if (task < 198 * 8) {
            int p  = task >> 3;
            int oc = task & 7;
            int rowi = p / 66;
            int col  = p - rowi * 66;
            int sr = i0 - 1 + rowi;
            int hc = j0 - 1 + col;
            bool ok = (sr >= 0) && (sr < HN) && (hc >= 0) && (hc < WN);
            int srb = ok ? sr : 0;
            int hcb = ok ? hc : 0;
            uint4 v = *(const uint4*)(xt + (((size_t)b * HN + srb) * WN + hcb) * 64 + oc * 8);
            if (!ok) v = (uint4){0u, 0u, 0u, 0u};
            *(uint4*)(sm + p * CPAD + oc * 8) = v;
        }
    }

    __syncthreads();

    // ---- MFMA: 4 n-subtiles x 9 taps x 2 k-chunks = 72 ----
    f32x4 acc[4] = {};
    const unsigned short* bb0 = sm + row * CPAD + (q << 3);
#pragma unroll
    for (int nt = 0; nt < 4; ++nt) {
#pragma unroll
        for (int t = 0; t < 9; ++t) {
            int a_ = t / 3, dxi = t - a_ * 3;
#pragma unroll
            for (int kc = 0; kc < 2; ++kc) {
                bf16x8 bv = *(const bf16x8*)(bb0 + (a_ * 66 + nt * 16 + dxi) * CPAD + kc * 32);
                acc[nt] = __builtin_amdgcn_mfma_f32_16x16x32_bf16(afrag[t][kc], bv, acc[nt], 0, 0, 0);
            }
        }
    }

    // ---- epilogue: bias, bf16-pack to LDS, coalesced NHWC store ----
    __syncthreads();   // all waves done reading sm before overwrite
    {
        int oc0 = (w << 4) + (q << 2);
        float b0 = bcv[oc0], b1 = bcv[oc0 + 1], b2 = bcv[oc0 + 2], b3 = bcv[oc0 + 3];
#pragma unroll
        for (int nt = 0; nt < 4; ++nt) {
            int px = nt * 16 + row;
            uint2 uu;
            uu.x = pkbf(acc[nt][0] + b0, acc[nt][1] + b1);
            uu.y = pkbf(acc[nt][2] + b2, acc[nt][3] + b3);
            *(uint2*)(sm + px * CPAD + oc0) = uu;
        }
    }
    __syncthreads();
    {
        size_t obase = ((size_t)b * HN + i0) * WN + j0;
#pragma unroll
        for (int it = 0; it < 2; ++it) {
            int task = tid + it * 256;       // 0..511
            int px = task >> 3, oc = task & 7;
            uint4 v = *(const uint4*)(sm + px * CPAD + oc * 8);
            *(uint4*)(featN + (obase + px) * 64 + oc * 8) = v;
        }
    }
}

// ---------------------------------------------------------------------------
// Kernel 2 (v6): NHWC gather + identity-folded expert GEMM.
//   v5 post-mortem: fp32 residual path cost 17.4 KB LDS (occupancy cap 5/CU)
//   + double staging + epilogue LDS reads. v6: out = (I + M)@fea0 with the
//   identity folded into Mavg by the prepass -> no fp32 fea32 buffer at all.
//   LDS 28.7 -> 11.5 KB; gather writes only the bf16 pack; epilogue is pure
//   register math + store. Residual passes through bf16 once (adds <~0.02).
// ---------------------------------------------------------------------------
#define BKP 72   // ushort stride of Bsv rows
__global__ __launch_bounds__(256) void out_kernel(
    const unsigned short* __restrict__ featN,  // [B,H,W,64] bf16
    const float* __restrict__ tblEntry,        // [256][8]
    const unsigned short* __restrict__ tblM,   // [pi][2][64][64] bf16 (Mavg has +I)
    const float* __restrict__ wce,             // [4,8,64]
    const float* __restrict__ wee,             // [4,64,8]
    const int* __restrict__ scale_p, const int* __restrict__ scale2_p,
    float* __restrict__ out)                   // [B,64,SH,SW]
{
    __shared__ __attribute__((aligned(16))) unsigned short Bsv[64 * BKP]; // 9216 B
    __shared__ int   cidx[4 * 64];
    __shared__ float cwt[4 * 64];
    float* midp = (float*)Bsv;                 // generic-path alias (needs 9216 B)

    int Bk = blockIdx.x;
    int T = gridDim.x;                         // 4608, %8==0
    int t = ((T & 7) == 0) ? ((Bk & 7) * (T >> 3) + (Bk >> 3)) : Bk;

    int tid = threadIdx.x;
    int g = __builtin_amdgcn_readfirstlane(tid >> 6);
    int lane = tid & 63;
    int pix0 = t * 64;
    int b = pix0 / (SH * SW);
    int r0 = pix0 - b * SH * SW;
    int i = r0 / SW;
    int j0 = r0 - i * SW;

    int sc = scale_p[0], sc2 = scale2_p[0];
    float scale = (float)sc, scale2 = (float)sc2;
    int pi = i - (i / sc) * sc;                // wave-uniform
    const float inv_wm1 = 2.f / (float)(WN - 1);
    const float inv_hm1 = 2.f / (float)(HN - 1);

    bool fast = (sc2 == 2 && sc <= 16);
    if (fast) {
        // ---- wave0: per-pixel corner indices + masked weights -> LDS ----
        if (tid < 64) {
            int px = tid;
            int jpx = j0 + px;
            int pjx = jpx - (jpx / sc2) * sc2;
            int entry = pi * sc2 + pjx;
            float offx = tblEntry[entry * 8 + 4];
            float offy = tblEntry[entry * 8 + 5];
            float gx = ((jpx + 0.5f) / scale2 - 0.5f) * inv_wm1 - 1.f + offx * inv_wm1;
            float gy = ((i + 0.5f) / scale  - 0.5f) * inv_hm1 - 1.f + offy * inv_hm1;
            float ix = ((gx + 1.f) * WN - 1.f) * 0.5f;
            float iy = ((gy + 1.f) * HN - 1.f) * 0.5f;
            float fx0 = floorf(ix), fy0 = floorf(iy);
            int x0 = (int)fx0, y0 = (int)fy0;
            float wx1 = ix - fx0, wx0 = 1.f - wx1;
            float wy1 = iy - fy0, wy0 = 1.f - wy1;
            bool vx0 = (x0 >= 0) && (x0 <= WN - 1);
            bool vx1 = (x0 + 1 >= 0) && (x0 + 1 <= WN - 1);
            bool vy0 = (y0 >= 0) && (y0 <= HN - 1);
            bool vy1 = (y0 + 1 >= 0) && (y0 + 1 <= HN - 1);
            int x0c = min(max(x0, 0), WN - 1);
            int x1c = min(max(x0 + 1, 0), WN - 1);
            int y0c = min(max(y0, 0), HN - 1);
            int y1c = min(max(y0 + 1, 0), HN - 1);
            cidx[0 * 64 + px] = y0c * WN + x0c;
            cidx[1 * 64 + px] = y0c * WN + x1c;
            cidx[2 * 64 + px] = y1c * WN + x0c;
            cidx[3 * 64 + px] = y1c * WN + x1c;
            cwt[0 * 64 + px] = wx0 * wy0 * ((vx0 && vy0) ? 1.f : 0.f);
            cwt[1 * 64 + px] = wx1 * wy0 * ((vx1 && vy0) ? 1.f : 0.f);
            cwt[2 * 64 + px] = wx0 * wy1 * ((vx0 && vy1) ? 1.f : 0.f);
            cwt[3 * 64 + px] = wx1 * wy1 * ((vx1 && vy1) ? 1.f : 0.f);
        }

        // ---- A fragments (global, issue before barrier): (Mavg+I)/Mdiff ----
        int row = lane & 15;
        int kb  = (lane >> 4) << 3;
        const unsigned short* Mb = tblM + (size_t)pi * 2 * 4096 + (g * 16 + row) * 64 + kb;
        bf16x8 a1[2], a2[2];
        a1[0] = *(const bf16x8*)(Mb);
        a1[1] = *(const bf16x8*)(Mb + 32);
        a2[0] = *(const bf16x8*)(Mb + 4096);
        a2[1] = *(const bf16x8*)(Mb + 4096 + 32);

        __syncthreads();

        // ---- gather: 512 (px, ch-octet) tasks, 4 contiguous b128 each ----
        const unsigned short* fb = featN + (size_t)b * HW * 64;
#pragma unroll
        for (int it = 0; it < 2; ++it) {
            int task = tid + it * 256;
            int px = task >> 3, oct = task & 7;
            const unsigned short* fo = fb + oct * 8;
            float a8[8] = {};
#pragma unroll
            for (int k = 0; k < 4; ++k) {
                bf16x8 cv = *(const bf16x8*)(fo + (size_t)cidx[k * 64 + px] * 64);
                float wk = cwt[k * 64 + px];
#pragma unroll
                for (int e = 0; e < 8; ++e)
                    a8[e] += wk * bf2f((unsigned short)cv[e]);
            }
            uint4 pk;
            pk.x = pkbf(a8[0], a8[1]);
            pk.y = pkbf(a8[2], a8[3]);
            pk.z = pkbf(a8[4], a8[5]);
            pk.w = pkbf(a8[6], a8[7]);
            *(uint4*)(Bsv + px * BKP + oct * 8) = pk;
        }

        __syncthreads();

        // ---- MFMA: D1 = (Mavg+I)@fea0, D2 = Mdiff@fea0 ----
        f32x4 acc1[4] = {}, acc2[4] = {};
        const unsigned short* bp = Bsv + (lane & 15) * BKP + kb;
#pragma unroll
        for (int nt = 0; nt < 4; ++nt) {
            const unsigned short* bnt = bp + nt * 16 * BKP;
#pragma unroll
            for (int ks = 0; ks < 2; ++ks) {
                bf16x8 bf = *(const bf16x8*)(bnt + ks * 32);
                acc1[nt] = __builtin_amdgcn_mfma_f32_16x16x32_bf16(a1[ks], bf, acc1[nt], 0, 0, 0);
                acc2[nt] = __builtin_amdgcn_mfma_f32_16x16x32_bf16(a2[ks], bf, acc2[nt], 0, 0, 0);
            }
        }

        // ---- epilogue: parity sign, store (residual already in acc1) ----
        int q = lane >> 4;
#pragma unroll
        for (int rr = 0; rr < 4; ++rr) {
            int c = g * 16 + q * 4 + rr;
            size_t rowb = (size_t)(b * CN + c) * SH * SW + r0;
#pragma unroll
            for (int nt = 0; nt < 4; ++nt) {
                int n = (lane & 15) + nt * 16;
                float sgn = (n & 1) ? -1.f : 1.f;
                out[rowb + n] = acc1[nt][rr] + sgn * acc2[nt][rr];
            }
        }
    } else {
        // ---- generic path (not exercised at scale=2): NHWC scalar gather ----
        int j = j0 + lane;
        int r = r0 + lane;
        int pj = j - (j / sc2) * sc2;
        int entry = pi * sc2 + pj;
        float offx = tblEntry[entry * 8 + 4];
        float offy = tblEntry[entry * 8 + 5];
        float gx = ((j + 0.5f) / scale2 - 0.5f) * inv_wm1 - 1.f + offx * inv_wm1;
        float gy = ((i + 0.5f) / scale  - 0.5f) * inv_hm1 - 1.f + offy * inv_hm1;
        float ix = ((gx + 1.f) * WN - 1.f) * 0.5f;
        float iy = ((gy + 1.f) * HN - 1.f) * 0.5f;
        float fx0 = floorf(ix), fy0 = floorf(iy);
        int x0 = (int)fx0, y0 = (int)fy0;
        float wx1 = ix - fx0, wx0 = 1.f - wx1;
        float wy1 = iy - fy0, wy0 = 1.f - wy1;
        bool vx0 = (x0 >= 0) && (x0 <= WN - 1);
        bool vx1 = (x0 + 1 >= 0) && (x0 + 1 <= WN - 1);
        bool vy0 = (y0 >= 0) && (y0 <= HN - 1);
        bool vy1 = (y0 + 1 >= 0) && (y0 + 1 <= HN - 1);
        int x0c = min(max(x0, 0), WN - 1);
        int x1c = min(max(x0 + 1, 0), WN - 1);
        int y0c = min(max(y0, 0), HN - 1);
        int y1c = min(max(y0 + 1, 0), HN - 1);
        float w00 = wx0 * wy0 * ((vx0 && vy0) ? 1.f : 0.f);
        float w10 = wx1 * wy0 * ((vx1 && vy0) ? 1.f : 0.f);
        float w01 = wx0 * wy1 * ((vx0 && vy1) ? 1.f : 0.f);
        float w11 = wx1 * wy1 * ((vx1 && vy1) ? 1.f : 0.f);
        const unsigned short* fb = featN + ((size_t)b * HW) * 64;
        const unsigned short* p00 = fb + (size_t)(y0c * WN + x0c) * 64;
        const unsigned short* p10 = fb + (size_t)(y0c * WN + x1c) * 64;
        const unsigned short* p01 = fb + (size_t)(y1c * WN + x0c) * 64;
        const unsigned short* p11 = fb + (size_t)(y1c * WN + x1c) * 64;

        float f0[16];
#pragma unroll
        for (int cc = 0; cc < 16; ++cc) {
            int c = g * 16 + cc;
            f0[cc] = bf2f(p00[c]) * w00 + bf2f(p10[c]) * w10
                   + bf2f(p01[c]) * w01 + bf2f(p11[c]) * w11;
        }

        float4 rw = *(const float4*)(tblEntry + entry * 8);
        float re[4] = {rw.x, rw.y, rw.z, rw.w};
        float part[4][8];
#pragma unroll
        for (int e = 0; e < 4; ++e) {
#pragma unroll
            for (int k = 0; k < 8; ++k) {
                const float* wrow = wce + (e * 8 + k) * 64 + g * 16;
                float d = 0.f;
#pragma unroll
                for (int cc = 0; cc < 16; ++cc) d += wrow[cc] * f0[cc];
                part[e][k] = d;
            }
        }
#pragma unroll
        for (int k = 0; k < 8; ++k) {
            float m = re[0] * part[0][k] + re[1] * part[1][k]
                    + re[2] * part[2][k] + re[3] * part[3][k];
            midp[(g * 64 + lane) * 9 + k] = m;
        }
        __syncthreads();
        float mid[8];
#pragma unroll
        for (int k = 0; k < 8; ++k)
            mid[k] = midp[(0 * 64 + lane) * 9 + k] + midp[(1 * 64 + lane) * 9 + k]
                   + midp[(2 * 64 + lane) * 9 + k] + midp[(3 * 64 + lane) * 9 + k];
#pragma unroll
        for (int cc = 0; cc < 16; ++cc) {
            int c = g * 16 + cc;
            float v = f0[cc];
#pragma unroll
            for (int e = 0; e < 4; ++e) {
                const float* wrow = wee + (e * 64 + c) * 8;
                float d = 0.f;
#pragma unroll
                for (int k = 0; k < 8; ++k) d += wrow[k] * mid[k];
                v += re[e] * d;
            }
            out[(size_t)(b * CN + c) * SH * SW + r] = v;
        }
    }
}

extern "C" void kernel_launch(void* const* d_in, const int* in_sizes, int n_in,
                              void* d_out, int out_size, void* d_ws, size_t ws_size,
                              hipStream_t stream) {
    const float* x    = (const float*)d_in[0];
    const float* wce  = (const float*)d_in[1];
    const float* wee  = (const float*)d_in[2];
    const float* wb1  = (const float*)d_in[3];
    const float* bb1  = (const float*)d_in[4];
    const float* wb2  = (const float*)d_in[5];
    const float* bb2  = (const float*)d_in[6];
    const float* wr   = (const float*)d_in[7];
    const float* br   = (const float*)d_in[8];
    const float* wo   = (const float*)d_in[9];
    const float* bo   = (const float*)d_in[10];
    const float* wcv  = (const float*)d_in[11];
    const float* bcv  = (const float*)d_in[12];
    const int*   scale  = (const int*)d_in[13];
    const int*   scale2 = (const int*)d_in[14];
    float* out = (float*)d_out;

    // workspace layout (16B-aligned chunks)
    unsigned short* featN = (unsigned short*)d_ws;                  // BN*HW*64 bf16 = 9.44 MB
    float* tblEntry = (float*)((char*)d_ws + (size_t)BN * HW * 64 * 2);   // 8 KB
    unsigned short* tblM = (unsigned short*)((char*)tblEntry + 2048 * 4); // 256 KB
    unsigned short* tblW = tblM + 16 * 2 * 4096;                    // 72 KB
    unsigned short* xt   = tblW + 4 * 9 * 2 * 64 * 8;               // 9.44 MB

    prepass_kernel<<<TRB + 1 + TBLB, 256, 0, stream>>>(
        x, wcv, wb1, bb1, wb2, bb2, wr, br, wo, bo,
        wce, wee, scale, scale2, xt, tblW, tblEntry, tblM);
    feat_kernel<<<TRB, 256, 0, stream>>>(xt, tblW, bcv, featN);
    out_kernel<<<BN * SH * SW / 64, 256, 0, stream>>>(featN, tblEntry, tblM,
                                                      wce, wee, scale, scale2, out);
}